// Round 1
// baseline (59.478 us; speedup 1.0000x reference)
//
#include <hip/hip_runtime.h>

#define NSEG 4096
// emb dims: emb_a [N,256], emb_b [N,256]; combined = 512; out = 32 per segment.

__global__ __launch_bounds__(128, 8) void seg_pool_proj_kernel(
    const float* __restrict__ emb_a,
    const float* __restrict__ emb_b,
    const int*   __restrict__ seg,    // [nrows], sorted ascending
    const float* __restrict__ W,      // [32, 512]
    const float* __restrict__ bias,   // [32]
    float*       __restrict__ out,    // [NSEG, 32]
    int nrows)
{
    const int s = blockIdx.x;
    const int t = threadIdx.x;

    __shared__ int   bounds[2];
    __shared__ float pooled[512];

    // Segment boundaries via lower_bound (ids are sorted). 16 iters, cached.
    if (t < 2) {
        int target = s + t;
        int lo = 0, hi = nrows;
        while (lo < hi) {
            int mid = (lo + hi) >> 1;
            if (seg[mid] < target) lo = mid + 1; else hi = mid;
        }
        bounds[t] = lo;
    }
    __syncthreads();
    const int start = bounds[0];
    const int end   = bounds[1];
    const int cnt   = end - start;

    // Each thread owns 4 consecutive columns (float4).
    // t in [0,64): emb_a cols [4t, 4t+4);  t in [64,128): emb_b cols.
    const float*  base = (t < 64) ? emb_a : emb_b;
    const int     colg = (t & 63);
    const float4* src  = reinterpret_cast<const float4*>(base) + colg; // row stride = 64 float4

    float4 acc = make_float4(0.f, 0.f, 0.f, 0.f);
    for (int r = start; r < end; ++r) {
        float4 v = src[(size_t)r * 64];
        acc.x += v.x; acc.y += v.y; acc.z += v.z; acc.w += v.w;
    }
    const float inv = 1.0f / (float)max(cnt, 1);
    acc.x *= inv; acc.y *= inv; acc.z *= inv; acc.w *= inv;

    // pooled layout: [0,256) from emb_a, [256,512) from emb_b
    const int cbase = ((t >> 6) << 8) + (colg << 2);
    pooled[cbase + 0] = acc.x;
    pooled[cbase + 1] = acc.y;
    pooled[cbase + 2] = acc.z;
    pooled[cbase + 3] = acc.w;
    __syncthreads();

    // Projection: out[j] = bias[j] + sum_d pooled[d] * W[j*512 + d].
    // 4 lanes per output channel j = t>>2; lane quad (t&3) covers 128-wide d-slices.
    const int j  = t >> 2;
    const int d0 = (t & 3) << 7;
    const float4* wrow = reinterpret_cast<const float4*>(W + j * 512 + d0);
    const float4* p4   = reinterpret_cast<const float4*>(pooled + d0);
    float sum = 0.f;
    #pragma unroll
    for (int d = 0; d < 32; ++d) {
        float4 w = wrow[d];
        float4 v = p4[d];
        sum += v.x * w.x + v.y * w.y + v.z * w.z + v.w * w.w;
    }
    // Reduce the 4 partials (lane quads are aligned within a wave).
    sum += __shfl_xor(sum, 1);
    sum += __shfl_xor(sum, 2);
    if ((t & 3) == 0) out[s * 32 + j] = sum + bias[j];
}

extern "C" void kernel_launch(void* const* d_in, const int* in_sizes, int n_in,
                              void* d_out, int out_size, void* d_ws, size_t ws_size,
                              hipStream_t stream) {
    const float* emb_a = (const float*)d_in[0];
    const float* emb_b = (const float*)d_in[1];
    const int*   seg   = (const int*)d_in[2];
    const float* W     = (const float*)d_in[3];
    const float* bias  = (const float*)d_in[4];
    float*       out   = (float*)d_out;
    const int nrows = in_sizes[2];

    seg_pool_proj_kernel<<<NSEG, 128, 0, stream>>>(emb_a, emb_b, seg, W, bias, out, nrows);
}